// Round 4
// baseline (58.440 us; speedup 1.0000x reference)
//
#include <hip/hip_runtime.h>

#define NLOC 100
#define TPB 512          // 8 waves
#define NWAVE 8
#define NLW 13           // ceil(NLOC / NWAVE)
#define CHUNK 2048       // pixels per block
#define TILE 16          // pixels per lane per register tile (2 tiles = 32 px/lane)

// ws layout: [0..4)  arrival counter (zeroed via hipMemsetAsync each call)
//            [16..)  pm [B*NLOC*nsub floats] | wts [B*NLOC floats] | nc [B ints]
// Every pm/wts/nc slot is written unconditionally every call -> no other init.

__global__ __launch_bounds__(TPB, 2)
void k_all(const float* __restrict__ loc, const float* __restrict__ unc,
           const float* __restrict__ prob, const float* __restrict__ tloc,
           float* __restrict__ pm, float* __restrict__ wts,
           int* __restrict__ nc, unsigned* __restrict__ counter,
           float* __restrict__ out, int P, int B, int nsub, int nblocks)
{
    __shared__ float2 s_t[NLW * NWAVE];   // padded to 104
    __shared__ int s_last;

    const int tid  = (int)threadIdx.x;
    const int wv   = tid >> 6;
    const int lane = tid & 63;
    const int sub  = (int)blockIdx.x;
    const int b    = (int)blockIdx.y;

    for (int i = tid; i < NLW * NWAVE; i += TPB)
        s_t[i] = (i < NLOC) ? reinterpret_cast<const float2*>(tloc)[b * NLOC + i]
                            : make_float2(0.f, 0.f);
    __syncthreads();

    // per-wave loc constants in registers
    float bxr[NLW], byr[NLW], m[NLW];
    #pragma unroll
    for (int i = 0; i < NLW; ++i) {
        float2 t = s_t[wv + i * NWAVE];
        bxr[i] = t.x; byr[i] = t.y;
        m[i] = 3.0e38f;
    }

    const int base = sub * CHUNK;
    const float2* locp  = reinterpret_cast<const float2*>(loc) + (size_t)b * P;
    const float*  probp = prob + (size_t)b * P;

    // two register tiles of 16 pixels/lane; sentinel for non-confident pixels
    #pragma unroll
    for (int t = 0; t < CHUNK / (TILE * 64); ++t) {
        float px[TILE], py[TILE], pa2[TILE];
        #pragma unroll
        for (int j = 0; j < TILE; ++j) {
            int p = base + t * (TILE * 64) + j * 64 + lane;
            bool inb = p < P;
            float pv  = inb ? probp[p] : 0.0f;
            float2 xy = inb ? locp[p] : make_float2(0.f, 0.f);
            bool conf = pv > 0.5f;
            px[j] = conf ? xy.x : 1.0e15f;    // sentinel: d^2 ~ 2e30, never wins
            py[j] = conf ? xy.y : 1.0e15f;
            pa2[j] = __builtin_fmaf(px[j], px[j], py[j] * py[j]);
        }
        #pragma unroll
        for (int i = 0; i < NLW; ++i) {
            float nbx = bxr[i] * -2.0f, nby = byr[i] * -2.0f;
            float mm = m[i];
            #pragma unroll
            for (int j = 0; j < TILE; ++j) {
                float d = __builtin_fmaf(px[j], nbx, pa2[j]);   // |a|^2 - 2bx*ax
                d = __builtin_fmaf(py[j], nby, d);              //        - 2by*ay
                mm = fminf(mm, d);
            }
            m[i] = mm;
        }
    }

    #pragma unroll
    for (int i = 0; i < NLW; ++i) {
        float mm = m[i];
        #pragma unroll
        for (int off = 32; off; off >>= 1)
            mm = fminf(mm, __shfl_xor(mm, off));
        int n = wv + i * NWAVE;
        if (lane == 0 && n < NLOC) {
            float b2 = __builtin_fmaf(bxr[i], bxr[i], byr[i] * byr[i]);
            pm[((size_t)b * NLOC + n) * nsub + sub] = fmaxf(mm + b2, 0.0f);  // min d^2
        }
    }

    // ordered scan for first-NLOC weights: wave 0 of sub==0 block per batch
    if (sub == 0 && wv == 0) {
        const float* up = unc + (size_t)b * P;
        const int nchunks = (P + 63) >> 6;
        int nconf = 0;
        for (int c = 0; c < nchunks; ++c) {
            if (nconf >= NLOC) break;
            int p = (c << 6) + lane;
            bool inb = p < P;
            float pv = probp[inb ? p : 0];
            bool conf = inb && (pv > 0.5f);
            unsigned long long mask = __ballot(conf);
            int pref = __popcll(mask & ((1ull << lane) - 1ull));
            int r = nconf + pref;
            if (conf && r < NLOC) wts[b * NLOC + r] = expf(-up[p]);
            nconf += __popcll(mask);
        }
        if (nconf < NLOC) {   // torch quirk: ranks continue into non-confident pixels
            int nnon = 0;
            for (int c = 0; c < nchunks; ++c) {
                if (nconf + nnon >= NLOC) break;
                int p = (c << 6) + lane;
                bool inb = p < P;
                float pv = probp[inb ? p : 0];
                bool nonc = inb && !(pv > 0.5f);
                unsigned long long mask = __ballot(nonc);
                int pref = __popcll(mask & ((1ull << lane) - 1ull));
                int r = nconf + nnon + pref;
                if (nonc && r < NLOC) wts[b * NLOC + r] = expf(-up[p]);
                nnon += __popcll(mask);
            }
        }
        if (lane == 0) nc[b] = (nconf > 0) ? 1 : 0;
    }

    // ---- arrival protocol: release writes, count in; last block finishes ----
    __threadfence();                 // each thread flushes its own global writes
    __syncthreads();                 // all fences done before the ticket
    if (tid == 0) {
        unsigned old = atomicAdd(counter, 1u);
        s_last = (old == (unsigned)(nblocks - 1)) ? 1 : 0;
    }
    __syncthreads();
    if (!s_last) return;
    __threadfence();                 // acquire: see all other blocks' writes

    // ---- finisher (runs in exactly one block) ----
    __shared__ float s_d[8 * NLOC];
    __shared__ float s_val[16];

    const int npairs = B * NLOC;
    for (int idx = tid; idx < npairs; idx += TPB) {
        const float4* pp = reinterpret_cast<const float4*>(pm + (size_t)idx * nsub);
        float mv = 3.0e38f;
        for (int k = 0; k < nsub / 4; ++k) {     // independent loads, overlapped
            float4 v = pp[k];
            mv = fminf(mv, fminf(fminf(v.x, v.y), fminf(v.z, v.w)));
        }
        s_d[idx] = sqrtf(mv);
    }
    __syncthreads();

    for (int bb = wv; bb < B; bb += NWAVE) {
        float sum = 0.0f;
        int vbase = 0;
        for (int c = 0; c < (NLOC + 63) / 64; ++c) {
            int j = c * 64 + lane;
            bool valid = false;
            if (j < NLOC) {
                float2 t = reinterpret_cast<const float2*>(tloc)[bb * NLOC + j];
                valid = (t.x >= 0.f) && (t.y >= 0.f);
            }
            unsigned long long mask = __ballot(valid);
            int rank = vbase + __popcll(mask & ((1ull << lane) - 1ull));
            if (valid) sum += s_d[bb * NLOC + j] * wts[bb * NLOC + rank];
            vbase += __popcll(mask);
        }
        #pragma unroll
        for (int off = 32; off; off >>= 1)
            sum += __shfl_xor(sum, off);
        if (lane == 0)
            s_val[bb] = (vbase == 0) ? 0.0f
                        : ((nc[bb] == 0) ? 10.0f : sum / (float)vbase);
    }
    __syncthreads();
    if (tid == 0) {
        float v = 0.0f;
        for (int i = 0; i < B; ++i) v += s_val[i];
        out[0] = v / (float)B;
    }
}

extern "C" void kernel_launch(void* const* d_in, const int* in_sizes, int n_in,
                              void* d_out, int out_size, void* d_ws, size_t ws_size,
                              hipStream_t stream)
{
    const float* loc  = (const float*)d_in[0];   // [B,H,W,2]
    const float* unc  = (const float*)d_in[1];   // [B,H,W,1]
    const float* tloc = (const float*)d_in[2];   // [B,N,2]
    const float* prob = (const float*)d_in[3];   // [B,1,H,W]
    float* out = (float*)d_out;

    int B = in_sizes[2] / (2 * NLOC);
    int P = in_sizes[1] / B;
    int nsub = (P + CHUNK - 1) / CHUNK;          // 32 for P=65536
    int nblocks = nsub * B;

    unsigned* counter = (unsigned*)d_ws;
    float* pm  = (float*)((char*)d_ws + 16);
    float* wts = pm + (size_t)B * NLOC * nsub;
    int*   ncp = (int*)(wts + (size_t)B * NLOC);

    hipMemsetAsync(counter, 0, sizeof(unsigned), stream);
    hipLaunchKernelGGL(k_all, dim3(nsub, B), dim3(TPB), 0, stream,
                       loc, unc, prob, tloc, pm, wts, ncp, counter, out,
                       P, B, nsub, nblocks);
}